// Round 6
// baseline (319.700 us; speedup 1.0000x reference)
//
#include <hip/hip_runtime.h>
#include <hip/hip_bf16.h>

typedef unsigned short u16;
typedef unsigned int u32;
typedef __attribute__((ext_vector_type(8))) short bf16x8;
typedef __attribute__((ext_vector_type(4))) float f32x4;
typedef __attribute__((ext_vector_type(4))) u32 u32x4;
typedef __attribute__((ext_vector_type(2))) u32 u32x2;

#define LQ 9216
#define CC 768
#define NH 6
#define DH 128
#define HH 96
#define WW 96

__device__ __forceinline__ u16 f2bf(float f) {
  union { float f; u32 u; } x; x.f = f;
  u32 r = x.u + 0x7fff + ((x.u >> 16) & 1);
  return (u16)(r >> 16);
}
__device__ __forceinline__ float u2f(u32 u) {
  union { u32 u; float f; } x; x.u = u; return x.f;
}
__device__ __forceinline__ float bf2f(u16 u) { return u2f(((u32)u) << 16); }

__device__ __forceinline__ void gl_lds16(const void* g, void* l) {
  __builtin_amdgcn_global_load_lds((const __attribute__((address_space(1))) void*)g,
                                   (__attribute__((address_space(3))) void*)l, 16, 0, 0);
}

__device__ __forceinline__ u32x2 pack4(float a, float b, float c, float d) {
  u32x2 o;
  o[0] = (u32)f2bf(a) | ((u32)f2bf(b) << 16);
  o[1] = (u32)f2bf(c) | ((u32)f2bf(d) << 16);
  return o;
}

// ---------------------------------------------------------------------------
// Two-rows-per-wave LayerNorm body (f32 input): 64 lanes x 3 float4 per row.
// ---------------------------------------------------------------------------
__device__ __forceinline__ void ln_wave2_body(const float* __restrict__ x, const float* __restrict__ w,
                                              const float* __restrict__ b, u16* __restrict__ out, int row0) {
  const int lane = threadIdx.x & 63;
  const float4* x0r = (const float4*)(x + (size_t)row0 * CC);
  const float4* x1r = x0r + (CC / 4);
  float4 va[3], vb[3];
  #pragma unroll
  for (int j = 0; j < 3; ++j) { va[j] = x0r[lane + 64 * j]; vb[j] = x1r[lane + 64 * j]; }
  const float4* wr = (const float4*)w;
  const float4* br = (const float4*)b;
  float4 wv[3], bv[3];
  #pragma unroll
  for (int j = 0; j < 3; ++j) { wv[j] = wr[lane + 64 * j]; bv[j] = br[lane + 64 * j]; }
  float sa = 0.f, ssa = 0.f, sb = 0.f, ssb = 0.f;
  #pragma unroll
  for (int j = 0; j < 3; ++j) {
    sa += va[j].x + va[j].y + va[j].z + va[j].w;
    ssa += va[j].x * va[j].x + va[j].y * va[j].y + va[j].z * va[j].z + va[j].w * va[j].w;
    sb += vb[j].x + vb[j].y + vb[j].z + vb[j].w;
    ssb += vb[j].x * vb[j].x + vb[j].y * vb[j].y + vb[j].z * vb[j].z + vb[j].w * vb[j].w;
  }
  #pragma unroll
  for (int o = 32; o > 0; o >>= 1) {
    sa += __shfl_xor(sa, o, 64);  ssa += __shfl_xor(ssa, o, 64);
    sb += __shfl_xor(sb, o, 64);  ssb += __shfl_xor(ssb, o, 64);
  }
  const float mua = sa * (1.f / 768.f);
  const float rsa = rsqrtf(ssa * (1.f / 768.f) - mua * mua + 1e-6f);
  const float mub = sb * (1.f / 768.f);
  const float rsb = rsqrtf(ssb * (1.f / 768.f) - mub * mub + 1e-6f);
  u32x2* o0 = (u32x2*)(out + (size_t)row0 * CC);
  u32x2* o1 = o0 + (CC / 4);
  #pragma unroll
  for (int j = 0; j < 3; ++j) {
    o0[lane + 64 * j] = pack4((va[j].x - mua) * rsa * wv[j].x + bv[j].x,
                              (va[j].y - mua) * rsa * wv[j].y + bv[j].y,
                              (va[j].z - mua) * rsa * wv[j].z + bv[j].z,
                              (va[j].w - mua) * rsa * wv[j].w + bv[j].w);
    o1[lane + 64 * j] = pack4((vb[j].x - mub) * rsb * wv[j].x + bv[j].x,
                              (vb[j].y - mub) * rsb * wv[j].y + bv[j].y,
                              (vb[j].z - mub) * rsb * wv[j].z + bv[j].z,
                              (vb[j].w - mub) * rsb * wv[j].w + bv[j].w);
  }
}

// ---------------------------------------------------------------------------
// Prelude: vectorized weight prep + 3 LayerNorms, one flattened dispatch.
// blocks [0,2304): w4 fp32->bf16 (float4/thread)
// blocks [2304,2496): cat mats    (float4/thread, zero-padded rows)
// block  2496: padded biases      (scalar)
// blocks [2497, 2497+3*1152): LN rows, 8 rows per block (2/wave)
// ---------------------------------------------------------------------------
#define PREP_BLKS 2497
__global__ __launch_bounds__(256)
void prelude(const float* __restrict__ vp, const float* __restrict__ op,
             const float* __restrict__ vp2, const float* __restrict__ op2,
             const float* __restrict__ so, const float* __restrict__ aw,
             const float* __restrict__ so2, const float* __restrict__ aw2,
             const float* __restrict__ so_b, const float* __restrict__ aw_b,
             const float* __restrict__ so2_b, const float* __restrict__ aw2_b,
             u16* __restrict__ w4, u16* __restrict__ cat1, u16* __restrict__ cat2,
             float* __restrict__ b1, float* __restrict__ b2,
             const float* __restrict__ x0, const float* __restrict__ w0, const float* __restrict__ bb0, u16* __restrict__ o0,
             const float* __restrict__ x1, const float* __restrict__ w1, const float* __restrict__ bb1, u16* __restrict__ o1,
             const float* __restrict__ x2, const float* __restrict__ w2, const float* __restrict__ bb2, u16* __restrict__ o2) {
  const int blk = blockIdx.x;
  if (blk < 2304) {
    const int i = blk * 256 + threadIdx.x;          // float4 index, 4*589824/4 total
    const int m = i / 147456, r = i - m * 147456;   // 589824/4 per matrix
    const float* s = (m == 0) ? vp : (m == 1) ? op : (m == 2) ? vp2 : op2;
    const float4 v = ((const float4*)s)[r];
    ((u32x2*)w4)[i] = pack4(v.x, v.y, v.z, v.w);
  } else if (blk < 2496) {
    const int j = (blk - 2304) * 256 + threadIdx.x; // float4 index, 2*98304/4 total
    const int which = j / 24576, r4 = j - which * 24576;
    const int e = r4 * 4;
    const int row = e / 768, colr = e - row * 768;
    float4 v = {0.f, 0.f, 0.f, 0.f};
    if (row < 48) v = ((const float4*)(which ? so2 : so))[(row * 768 + colr) >> 2];
    else if (row < 72) v = ((const float4*)(which ? aw2 : aw))[((row - 48) * 768 + colr) >> 2];
    ((u32x2*)(which ? cat2 : cat1))[r4] = pack4(v.x, v.y, v.z, v.w);
  } else if (blk == 2496) {
    const int t = threadIdx.x;
    const int which = t >> 7, row = t & 127;
    float v = 0.f;
    if (row < 48) v = (which ? so2_b : so_b)[row];
    else if (row < 72) v = (which ? aw2_b : aw_b)[row - 48];
    (which ? b2 : b1)[row] = v;
  } else {
    const int r = blk - PREP_BLKS;
    const int sel = r / 1152;
    const int row0 = (r - sel * 1152) * 8 + (threadIdx.x >> 6) * 2;
    const float* x = (sel == 0) ? x0 : (sel == 1) ? x1 : x2;
    const float* w = (sel == 0) ? w0 : (sel == 1) ? w1 : w2;
    const float* b = (sel == 0) ? bb0 : (sel == 1) ? bb1 : bb2;
    u16* o = (sel == 0) ? o0 : (sel == 1) ? o1 : o2;
    ln_wave2_body(x, w, b, o, row0);
  }
}

// ---------------------------------------------------------------------------
// Two-rows-per-wave LayerNorm, bf16 input -> bf16 output (for qbuf).
// ---------------------------------------------------------------------------
__global__ __launch_bounds__(256)
void ln_bf16_to_bf16(const u16* __restrict__ x, const float* __restrict__ w,
                     const float* __restrict__ b, u16* __restrict__ out) {
  const int row0 = blockIdx.x * 8 + (threadIdx.x >> 6) * 2;
  const int lane = threadIdx.x & 63;
  const u32x2* x0r = (const u32x2*)(x + (size_t)row0 * CC);
  const u32x2* x1r = x0r + (CC / 4);
  float va[3][4], vb[3][4];
  #pragma unroll
  for (int j = 0; j < 3; ++j) {
    const u32x2 ua = x0r[lane + 64 * j];
    const u32x2 ub = x1r[lane + 64 * j];
    va[j][0] = u2f(ua[0] << 16); va[j][1] = u2f(ua[0] & 0xffff0000u);
    va[j][2] = u2f(ua[1] << 16); va[j][3] = u2f(ua[1] & 0xffff0000u);
    vb[j][0] = u2f(ub[0] << 16); vb[j][1] = u2f(ub[0] & 0xffff0000u);
    vb[j][2] = u2f(ub[1] << 16); vb[j][3] = u2f(ub[1] & 0xffff0000u);
  }
  float sa = 0.f, ssa = 0.f, sb = 0.f, ssb = 0.f;
  #pragma unroll
  for (int j = 0; j < 3; ++j)
    #pragma unroll
    for (int k = 0; k < 4; ++k) {
      sa += va[j][k]; ssa += va[j][k] * va[j][k];
      sb += vb[j][k]; ssb += vb[j][k] * vb[j][k];
    }
  #pragma unroll
  for (int o = 32; o > 0; o >>= 1) {
    sa += __shfl_xor(sa, o, 64);  ssa += __shfl_xor(ssa, o, 64);
    sb += __shfl_xor(sb, o, 64);  ssb += __shfl_xor(ssb, o, 64);
  }
  const float mua = sa * (1.f / 768.f);
  const float rsa = rsqrtf(ssa * (1.f / 768.f) - mua * mua + 1e-6f);
  const float mub = sb * (1.f / 768.f);
  const float rsb = rsqrtf(ssb * (1.f / 768.f) - mub * mub + 1e-6f);
  const float4* wr = (const float4*)w;
  const float4* br = (const float4*)b;
  u32x2* or0 = (u32x2*)(out + (size_t)row0 * CC);
  u32x2* or1 = or0 + (CC / 4);
  #pragma unroll
  for (int j = 0; j < 3; ++j) {
    const float4 wv = wr[lane + 64 * j];
    const float4 bv = br[lane + 64 * j];
    or0[lane + 64 * j] = pack4((va[j][0] - mua) * rsa * wv.x + bv.x,
                               (va[j][1] - mua) * rsa * wv.y + bv.y,
                               (va[j][2] - mua) * rsa * wv.z + bv.z,
                               (va[j][3] - mua) * rsa * wv.w + bv.w);
    or1[lane + 64 * j] = pack4((vb[j][0] - mub) * rsb * wv.x + bv.x,
                               (vb[j][1] - mub) * rsb * wv.y + bv.y,
                               (vb[j][2] - mub) * rsb * wv.z + bv.z,
                               (vb[j][3] - mub) * rsb * wv.w + bv.w);
  }
}

// ---------------------------------------------------------------------------
// bf16 MFMA GEMM core: TM x 64 tile, BK=64 as two 32-col panels. LDS passed in.
// MODE 0: bf16 out
// MODE 1: f32 out
// MODE 2: bf16 out = f2bf(res_f32[o] + gamma[n]*(acc+bias))   (round-1 op)
// MODE 3: f32 out  = bf2f(res_bf16[o]) + gamma[n]*(acc+bias)  (round-2 op)
// ---------------------------------------------------------------------------
template <int TM, int MODE>
__device__ __forceinline__ void gemm_core(u16* __restrict__ As, u16* __restrict__ Bs,
                                          const u16* __restrict__ A, const u16* __restrict__ W,
                                          const float* __restrict__ bias, void* __restrict__ outv,
                                          const void* __restrict__ res, const float* __restrict__ gamma,
                                          int N, int K, int m0, int n0) {
  constexpr int FI = TM / 32;
  constexpr int NIA = TM / 32;
  const int tid = threadIdx.x;
  const int wv = tid >> 6, lane = tid & 63;
  const int quad = lane >> 4, l16 = lane & 15;
  const int wm = wv & 1, wn = wv >> 1;
  const int sr4 = lane >> 2;
  const int sc = (lane & 3) << 3;

  f32x4 acc[FI][2];
  #pragma unroll
  for (int i = 0; i < FI; ++i)
    #pragma unroll
    for (int j = 0; j < 2; ++j)
      acc[i][j] = (f32x4){0.f, 0.f, 0.f, 0.f};

  for (int k0 = 0; k0 < K; k0 += 64) {
    __syncthreads();
    #pragma unroll
    for (int j = 0; j < NIA; ++j) {
      const int g = wv * NIA + j;
      const int p = g & 1, rb = g >> 1;
      gl_lds16(A + (size_t)(m0 + rb * 16 + sr4) * K + (k0 + p * 32 + sc),
               (char*)As + p * (TM * 64) + rb * 1024 + lane * 16);
    }
    #pragma unroll
    for (int j = 0; j < 2; ++j) {
      const int g = wv * 2 + j;
      const int p = g & 1, rb = g >> 1;
      gl_lds16(W + (size_t)(n0 + rb * 16 + sr4) * K + (k0 + p * 32 + sc),
               (char*)Bs + p * 4096 + rb * 1024 + lane * 16);
    }
    __syncthreads();
    #pragma unroll
    for (int kk = 0; kk < 2; ++kk) {
      bf16x8 af[FI], bfr[2];
      #pragma unroll
      for (int i = 0; i < FI; ++i)
        af[i] = *(const bf16x8*)(As + kk * (TM * 32) + (wm * (TM / 2) + i * 16 + l16) * 32 + quad * 8);
      #pragma unroll
      for (int j = 0; j < 2; ++j)
        bfr[j] = *(const bf16x8*)(Bs + kk * 2048 + (wn * 32 + j * 16 + l16) * 32 + quad * 8);
      #pragma unroll
      for (int i = 0; i < FI; ++i)
        #pragma unroll
        for (int j = 0; j < 2; ++j)
          acc[i][j] = __builtin_amdgcn_mfma_f32_16x16x32_bf16(af[i], bfr[j], acc[i][j], 0, 0, 0);
    }
  }

  #pragma unroll
  for (int i = 0; i < FI; ++i) {
    #pragma unroll
    for (int j = 0; j < 2; ++j) {
      const int col = n0 + wn * 32 + j * 16 + l16;
      const float bs = bias[col];
      #pragma unroll
      for (int r = 0; r < 4; ++r) {
        const int row = m0 + wm * (TM / 2) + i * 16 + quad * 4 + r;
        const float v = acc[i][j][r] + bs;
        const size_t o = (size_t)row * N + col;
        if (MODE == 0) ((u16*)outv)[o] = f2bf(v);
        else if (MODE == 1) ((float*)outv)[o] = v;
        else if (MODE == 2) ((u16*)outv)[o] = f2bf(((const float*)res)[o] + gamma[col] * v);
        else ((float*)outv)[o] = bf2f(((const u16*)res)[o]) + gamma[col] * v;
      }
    }
  }
}

// Fused dispatch: both value-projection GEMMs (1728 blocks) + round-1 small
// offset/aw GEMM (288 blocks) in one 2016-block launch.
__global__ __launch_bounds__(256, 5)
void gemm_fused1(const u16* __restrict__ fn, const u16* __restrict__ wv1, const float* __restrict__ vb1, u16* __restrict__ val1,
                 const u16* __restrict__ fn2, const u16* __restrict__ wv2, const float* __restrict__ vb2, u16* __restrict__ val2,
                 const u16* __restrict__ qn, const u16* __restrict__ cat1, const float* __restrict__ b1, float* __restrict__ offaw) {
  __shared__ u16 As[128 * 64];
  __shared__ u16 Bs[64 * 64];
  const int id = blockIdx.x;
  if (id < 1728) {
    const int z = id / 864, rem = id - z * 864;
    const int x = rem % 72, y = rem / 72;
    gemm_core<128, 0>(As, Bs, z ? fn2 : fn, z ? wv2 : wv1, z ? vb2 : vb1,
                      (void*)(z ? val2 : val1), nullptr, nullptr, CC, CC, x * 128, y * 64);
  } else {
    const int sid = id - 1728;
    const int x = sid % 144, y = sid / 144;
    gemm_core<64, 1>(As, Bs, qn, cat1, b1, (void*)offaw, nullptr, nullptr, 128, CC, x * 64, y * 64);
  }
}

template <int MODE>
__global__ __launch_bounds__(256, 5)
void gemm_bt(const u16* __restrict__ A, const u16* __restrict__ W,
             const float* __restrict__ bias, void* __restrict__ outv,
             const void* __restrict__ res, const float* __restrict__ gamma,
             int N, int K) {
  __shared__ u16 As[128 * 64];
  __shared__ u16 Bs[64 * 64];
  gemm_core<128, MODE>(As, Bs, A, W, bias, outv, res, gamma, N, K, blockIdx.x * 128, blockIdx.y * 64);
}

__global__ __launch_bounds__(256, 5)
void gemm_small(const u16* __restrict__ A, const u16* __restrict__ W,
                const float* __restrict__ bias, float* __restrict__ out,
                int N, int K) {
  __shared__ u16 As[64 * 64];
  __shared__ u16 Bs[64 * 64];
  gemm_core<64, 1>(As, Bs, A, W, bias, (void*)out, nullptr, nullptr, N, K, blockIdx.x * 64, blockIdx.y * 64);
}

// ---------------------------------------------------------------------------
// Deformable sampling: 16 lanes per (q,h), each lane 8 channels (dwordx4).
// All 16 corner loads batched (addresses+weights precomputed) for max MLP.
// ---------------------------------------------------------------------------
__global__ __launch_bounds__(256)
void msds_sample(const u16* __restrict__ value, const float* __restrict__ offaw,
                 const float* __restrict__ ref, u16* __restrict__ out) {
  const int t = blockIdx.x * 256 + threadIdx.x;
  const int pi = t >> 4;
  const int gl = t & 15;
  const int q = pi / NH;
  const int h = pi - q * NH;
  const float4* oaf = (const float4*)(offaw + (size_t)q * 128);
  const float4 of0 = oaf[h * 2];
  const float4 of1 = oaf[h * 2 + 1];
  const float4 lg = oaf[12 + h];
  const float2 rp = ((const float2*)ref)[q];
  const float rx = rp.x * (float)WW - 0.5f;
  const float ry = rp.y * (float)HH - 0.5f;

  const float mx = fmaxf(fmaxf(lg.x, lg.y), fmaxf(lg.z, lg.w));
  const float e0 = __expf(lg.x - mx), e1 = __expf(lg.y - mx);
  const float e2 = __expf(lg.z - mx), e3 = __expf(lg.w - mx);
  const float inv = 1.f / (e0 + e1 + e2 + e3);
  const float wp[4] = {e0 * inv, e1 * inv, e2 * inv, e3 * inv};
  const float ox[4] = {of0.x, of0.z, of1.x, of1.z};
  const float oy[4] = {of0.y, of0.w, of1.y, of1.w};

  const u16* vbase = value + h * DH + gl * 8;
  float w16[16];
  int  idx16[16];
  #pragma unroll
  for (int p = 0; p < 4; ++p) {
    const float px = rx + ox[p];
    const float py = ry + oy[p];
    const float fxf = floorf(px), fyf = floorf(py);
    const int x0 = (int)fxf, y0 = (int)fyf;
    const float fx = px - fxf, fy = py - fyf;
    const float cw[4] = {wp[p] * (1.f - fy) * (1.f - fx), wp[p] * (1.f - fy) * fx,
                         wp[p] * fy * (1.f - fx),         wp[p] * fy * fx};
    #pragma unroll
    for (int c = 0; c < 4; ++c) {
      const int yy = y0 + (c >> 1);
      const int xx = x0 + (c & 1);
      const bool valid = (yy >= 0) & (yy < HH) & (xx >= 0) & (xx < WW);
      const int yc = min(max(yy, 0), HH - 1);
      const int xc = min(max(xx, 0), WW - 1);
      w16[p * 4 + c] = valid ? cw[c] : 0.f;
      idx16[p * 4 + c] = yc * WW + xc;
    }
  }
  u32x4 d[16];
  #pragma unroll
  for (int tt = 0; tt < 16; ++tt)
    d[tt] = *(const u32x4*)(vbase + (size_t)idx16[tt] * CC);

  float acc[8];
  #pragma unroll
  for (int k = 0; k < 8; ++k) acc[k] = 0.f;
  #pragma unroll
  for (int tt = 0; tt < 16; ++tt) {
    const float w2 = w16[tt];
    #pragma unroll
    for (int k = 0; k < 4; ++k) {
      acc[2 * k]     += w2 * u2f(d[tt][k] << 16);
      acc[2 * k + 1] += w2 * u2f(d[tt][k] & 0xffff0000u);
    }
  }
  u32x4 o;
  #pragma unroll
  for (int k = 0; k < 4; ++k)
    o[k] = (u32)f2bf(acc[2 * k]) | ((u32)f2bf(acc[2 * k + 1]) << 16);
  *(u32x4*)(out + (size_t)q * CC + h * DH + gl * 8) = o;
}

// ---------------------------------------------------------------------------
extern "C" void kernel_launch(void* const* d_in, const int* in_sizes, int n_in,
                              void* d_out, int out_size, void* d_ws, size_t ws_size,
                              hipStream_t stream) {
  const float* query = (const float*)d_in[0];
  const float* refp  = (const float*)d_in[1];
  const float* feat  = (const float*)d_in[2];
  const float* feat2 = (const float*)d_in[3];
  const float* qn_w = (const float*)d_in[6];
  const float* qn_b = (const float*)d_in[7];
  const float* fn_w = (const float*)d_in[8];
  const float* fn_b = (const float*)d_in[9];
  const float* so_w = (const float*)d_in[10];
  const float* so_b = (const float*)d_in[11];
  const float* aw_w = (const float*)d_in[12];
  const float* aw_b = (const float*)d_in[13];
  const float* vp_w = (const float*)d_in[14];
  const float* vp_b = (const float*)d_in[15];
  const float* op_w = (const float*)d_in[16];
  const float* op_b = (const float*)d_in[17];
  const float* gamma = (const float*)d_in[18];
  const float* qn2_w = (const float*)d_in[19];
  const float* qn2_b = (const float*)d_in[20];
  const float* fn2_w = (const float*)d_in[21];
  const float* fn2_b = (const float*)d_in[22];
  const float* so2_w = (const float*)d_in[23];
  const float* so2_b = (const float*)d_in[24];
  const float* aw2_w = (const float*)d_in[25];
  const float* aw2_b = (const float*)d_in[26];
  const float* vp2_w = (const float*)d_in[27];
  const float* vp2_b = (const float*)d_in[28];
  const float* op2_w = (const float*)d_in[29];
  const float* op2_b = (const float*)d_in[30];
  const float* gamma2 = (const float*)d_in[31];

  char* ws = (char*)d_ws;
  size_t off = 0;
  auto alloc = [&](size_t bytes) -> void* {
    void* p = ws + off;
    off += (bytes + 255) & ~(size_t)255;
    return p;
  };
  u16* w4    = (u16*)alloc((size_t)4 * 589824 * 2);
  u16* cat1  = (u16*)alloc((size_t)98304 * 2);
  u16* cat2  = (u16*)alloc((size_t)98304 * 2);
  float* b1  = (float*)alloc(128 * 4);
  float* b2  = (float*)alloc(128 * 4);
  u16* qn    = (u16*)alloc((size_t)LQ * CC * 2);  // reused as qn2
  u16* fn    = (u16*)alloc((size_t)LQ * CC * 2);  // reused as a_pre
  u16* fn2   = (u16*)alloc((size_t)LQ * CC * 2);  // reused as a2_pre
  u16* val1  = (u16*)alloc((size_t)LQ * CC * 2);
  u16* val2  = (u16*)alloc((size_t)LQ * CC * 2);
  float* offaw = (float*)alloc((size_t)LQ * 128 * 4);  // both rounds
  u16* qbuf  = (u16*)alloc((size_t)LQ * CC * 2);       // bf16 residual q

  dim3 blk(256);
  dim3 gbig(LQ / 128, CC / 64), gsm(LQ / 64, 2);

  prelude<<<PREP_BLKS + 3 * 1152, blk, 0, stream>>>(
      vp_w, op_w, vp2_w, op2_w, so_w, aw_w, so2_w, aw2_w,
      so_b, aw_b, so2_b, aw2_b, w4, cat1, cat2, b1, b2,
      query, qn_w, qn_b, qn,
      feat, fn_w, fn_b, fn,
      feat2, fn2_w, fn2_b, fn2);
  gemm_fused1<<<2016, blk, 0, stream>>>(fn, w4, vp_b, val1,
                                        fn2, w4 + 2 * 589824, vp2_b, val2,
                                        qn, cat1, b1, offaw);
  msds_sample<<<LQ * NH / 16, blk, 0, stream>>>(val1, offaw, refp, fn);  // a_pre -> fn
  gemm_bt<2><<<gbig, blk, 0, stream>>>(fn, w4 + 589824, op_b, (void*)qbuf, query, gamma, CC, CC);
  ln_bf16_to_bf16<<<LQ / 8, blk, 0, stream>>>(qbuf, qn2_w, qn2_b, qn);  // qn2 -> qn
  gemm_small<<<gsm, blk, 0, stream>>>(qn, cat2, b2, offaw, 128, CC);
  msds_sample<<<LQ * NH / 16, blk, 0, stream>>>(val2, offaw, refp, fn2);  // a2_pre -> fn2
  gemm_bt<3><<<gbig, blk, 0, stream>>>(fn2, w4 + 3 * 589824, op2_b, d_out, qbuf, gamma2, CC, CC);
}

// Round 7
// 315.367 us; speedup vs baseline: 1.0137x; 1.0137x over previous
//
#include <hip/hip_runtime.h>
#include <hip/hip_bf16.h>

typedef unsigned short u16;
typedef unsigned int u32;
typedef __attribute__((ext_vector_type(8))) short bf16x8;
typedef __attribute__((ext_vector_type(4))) float f32x4;
typedef __attribute__((ext_vector_type(4))) u32 u32x4;
typedef __attribute__((ext_vector_type(2))) u32 u32x2;

#define LQ 9216
#define CC 768
#define NH 6
#define DH 128
#define HH 96
#define WW 96

__device__ __forceinline__ u16 f2bf(float f) {
  union { float f; u32 u; } x; x.f = f;
  u32 r = x.u + 0x7fff + ((x.u >> 16) & 1);
  return (u16)(r >> 16);
}
__device__ __forceinline__ float u2f(u32 u) {
  union { u32 u; float f; } x; x.u = u; return x.f;
}
__device__ __forceinline__ float bf2f(u16 u) { return u2f(((u32)u) << 16); }

__device__ __forceinline__ void gl_lds16(const void* g, void* l) {
  __builtin_amdgcn_global_load_lds((const __attribute__((address_space(1))) void*)g,
                                   (__attribute__((address_space(3))) void*)l, 16, 0, 0);
}

__device__ __forceinline__ u32x2 pack4(float a, float b, float c, float d) {
  u32x2 o;
  o[0] = (u32)f2bf(a) | ((u32)f2bf(b) << 16);
  o[1] = (u32)f2bf(c) | ((u32)f2bf(d) << 16);
  return o;
}

// XCD-aware swizzle for 864-block GEMMs (72 M-tiles x 12 N-tiles):
// each XCD owns a 9-tile M-stripe (1.75 MB A, L2-resident) swept over all
// 12 N-tiles (y cycles fastest in its temporal block sequence).
__device__ __forceinline__ void swz864(int b, int& m0, int& n0) {
  const int xcd = b & 7, g = b >> 3;
  const int y = g % 12, mloc = g / 12;
  m0 = (xcd * 9 + mloc) * 128;
  n0 = y * 64;
}

// ---------------------------------------------------------------------------
// Two-rows-per-wave LayerNorm body (f32 input): 64 lanes x 3 float4 per row.
// ---------------------------------------------------------------------------
__device__ __forceinline__ void ln_wave2_body(const float* __restrict__ x, const float* __restrict__ w,
                                              const float* __restrict__ b, u16* __restrict__ out, int row0) {
  const int lane = threadIdx.x & 63;
  const float4* x0r = (const float4*)(x + (size_t)row0 * CC);
  const float4* x1r = x0r + (CC / 4);
  float4 va[3], vb[3];
  #pragma unroll
  for (int j = 0; j < 3; ++j) { va[j] = x0r[lane + 64 * j]; vb[j] = x1r[lane + 64 * j]; }
  const float4* wr = (const float4*)w;
  const float4* br = (const float4*)b;
  float4 wv[3], bv[3];
  #pragma unroll
  for (int j = 0; j < 3; ++j) { wv[j] = wr[lane + 64 * j]; bv[j] = br[lane + 64 * j]; }
  float sa = 0.f, ssa = 0.f, sb = 0.f, ssb = 0.f;
  #pragma unroll
  for (int j = 0; j < 3; ++j) {
    sa += va[j].x + va[j].y + va[j].z + va[j].w;
    ssa += va[j].x * va[j].x + va[j].y * va[j].y + va[j].z * va[j].z + va[j].w * va[j].w;
    sb += vb[j].x + vb[j].y + vb[j].z + vb[j].w;
    ssb += vb[j].x * vb[j].x + vb[j].y * vb[j].y + vb[j].z * vb[j].z + vb[j].w * vb[j].w;
  }
  #pragma unroll
  for (int o = 32; o > 0; o >>= 1) {
    sa += __shfl_xor(sa, o, 64);  ssa += __shfl_xor(ssa, o, 64);
    sb += __shfl_xor(sb, o, 64);  ssb += __shfl_xor(ssb, o, 64);
  }
  const float mua = sa * (1.f / 768.f);
  const float rsa = rsqrtf(ssa * (1.f / 768.f) - mua * mua + 1e-6f);
  const float mub = sb * (1.f / 768.f);
  const float rsb = rsqrtf(ssb * (1.f / 768.f) - mub * mub + 1e-6f);
  u32x2* o0 = (u32x2*)(out + (size_t)row0 * CC);
  u32x2* o1 = o0 + (CC / 4);
  #pragma unroll
  for (int j = 0; j < 3; ++j) {
    o0[lane + 64 * j] = pack4((va[j].x - mua) * rsa * wv[j].x + bv[j].x,
                              (va[j].y - mua) * rsa * wv[j].y + bv[j].y,
                              (va[j].z - mua) * rsa * wv[j].z + bv[j].z,
                              (va[j].w - mua) * rsa * wv[j].w + bv[j].w);
    o1[lane + 64 * j] = pack4((vb[j].x - mub) * rsb * wv[j].x + bv[j].x,
                              (vb[j].y - mub) * rsb * wv[j].y + bv[j].y,
                              (vb[j].z - mub) * rsb * wv[j].z + bv[j].z,
                              (vb[j].w - mub) * rsb * wv[j].w + bv[j].w);
  }
}

// ---------------------------------------------------------------------------
// Prelude: vectorized weight prep + 3 LayerNorms, one flattened dispatch.
// ---------------------------------------------------------------------------
#define PREP_BLKS 2497
__global__ __launch_bounds__(256)
void prelude(const float* __restrict__ vp, const float* __restrict__ op,
             const float* __restrict__ vp2, const float* __restrict__ op2,
             const float* __restrict__ so, const float* __restrict__ aw,
             const float* __restrict__ so2, const float* __restrict__ aw2,
             const float* __restrict__ so_b, const float* __restrict__ aw_b,
             const float* __restrict__ so2_b, const float* __restrict__ aw2_b,
             u16* __restrict__ w4, u16* __restrict__ cat1, u16* __restrict__ cat2,
             float* __restrict__ b1, float* __restrict__ b2,
             const float* __restrict__ x0, const float* __restrict__ w0, const float* __restrict__ bb0, u16* __restrict__ o0,
             const float* __restrict__ x1, const float* __restrict__ w1, const float* __restrict__ bb1, u16* __restrict__ o1,
             const float* __restrict__ x2, const float* __restrict__ w2, const float* __restrict__ bb2, u16* __restrict__ o2) {
  const int blk = blockIdx.x;
  if (blk < 2304) {
    const int i = blk * 256 + threadIdx.x;
    const int m = i / 147456, r = i - m * 147456;
    const float* s = (m == 0) ? vp : (m == 1) ? op : (m == 2) ? vp2 : op2;
    const float4 v = ((const float4*)s)[r];
    ((u32x2*)w4)[i] = pack4(v.x, v.y, v.z, v.w);
  } else if (blk < 2496) {
    const int j = (blk - 2304) * 256 + threadIdx.x;
    const int which = j / 24576, r4 = j - which * 24576;
    const int e = r4 * 4;
    const int row = e / 768, colr = e - row * 768;
    float4 v = {0.f, 0.f, 0.f, 0.f};
    if (row < 48) v = ((const float4*)(which ? so2 : so))[(row * 768 + colr) >> 2];
    else if (row < 72) v = ((const float4*)(which ? aw2 : aw))[((row - 48) * 768 + colr) >> 2];
    ((u32x2*)(which ? cat2 : cat1))[r4] = pack4(v.x, v.y, v.z, v.w);
  } else if (blk == 2496) {
    const int t = threadIdx.x;
    const int which = t >> 7, row = t & 127;
    float v = 0.f;
    if (row < 48) v = (which ? so2_b : so_b)[row];
    else if (row < 72) v = (which ? aw2_b : aw_b)[row - 48];
    (which ? b2 : b1)[row] = v;
  } else {
    const int r = blk - PREP_BLKS;
    const int sel = r / 1152;
    const int row0 = (r - sel * 1152) * 8 + (threadIdx.x >> 6) * 2;
    const float* x = (sel == 0) ? x0 : (sel == 1) ? x1 : x2;
    const float* w = (sel == 0) ? w0 : (sel == 1) ? w1 : w2;
    const float* b = (sel == 0) ? bb0 : (sel == 1) ? bb1 : bb2;
    u16* o = (sel == 0) ? o0 : (sel == 1) ? o1 : o2;
    ln_wave2_body(x, w, b, o, row0);
  }
}

// ---------------------------------------------------------------------------
// Two-rows-per-wave LayerNorm, bf16 input -> bf16 output (for qbuf).
// ---------------------------------------------------------------------------
__global__ __launch_bounds__(256)
void ln_bf16_to_bf16(const u16* __restrict__ x, const float* __restrict__ w,
                     const float* __restrict__ b, u16* __restrict__ out) {
  const int row0 = blockIdx.x * 8 + (threadIdx.x >> 6) * 2;
  const int lane = threadIdx.x & 63;
  const u32x2* x0r = (const u32x2*)(x + (size_t)row0 * CC);
  const u32x2* x1r = x0r + (CC / 4);
  float va[3][4], vb[3][4];
  #pragma unroll
  for (int j = 0; j < 3; ++j) {
    const u32x2 ua = x0r[lane + 64 * j];
    const u32x2 ub = x1r[lane + 64 * j];
    va[j][0] = u2f(ua[0] << 16); va[j][1] = u2f(ua[0] & 0xffff0000u);
    va[j][2] = u2f(ua[1] << 16); va[j][3] = u2f(ua[1] & 0xffff0000u);
    vb[j][0] = u2f(ub[0] << 16); vb[j][1] = u2f(ub[0] & 0xffff0000u);
    vb[j][2] = u2f(ub[1] << 16); vb[j][3] = u2f(ub[1] & 0xffff0000u);
  }
  float sa = 0.f, ssa = 0.f, sb = 0.f, ssb = 0.f;
  #pragma unroll
  for (int j = 0; j < 3; ++j)
    #pragma unroll
    for (int k = 0; k < 4; ++k) {
      sa += va[j][k]; ssa += va[j][k] * va[j][k];
      sb += vb[j][k]; ssb += vb[j][k] * vb[j][k];
    }
  #pragma unroll
  for (int o = 32; o > 0; o >>= 1) {
    sa += __shfl_xor(sa, o, 64);  ssa += __shfl_xor(ssa, o, 64);
    sb += __shfl_xor(sb, o, 64);  ssb += __shfl_xor(ssb, o, 64);
  }
  const float mua = sa * (1.f / 768.f);
  const float rsa = rsqrtf(ssa * (1.f / 768.f) - mua * mua + 1e-6f);
  const float mub = sb * (1.f / 768.f);
  const float rsb = rsqrtf(ssb * (1.f / 768.f) - mub * mub + 1e-6f);
  const float4* wr = (const float4*)w;
  const float4* br = (const float4*)b;
  u32x2* or0 = (u32x2*)(out + (size_t)row0 * CC);
  u32x2* or1 = or0 + (CC / 4);
  #pragma unroll
  for (int j = 0; j < 3; ++j) {
    const float4 wv = wr[lane + 64 * j];
    const float4 bv = br[lane + 64 * j];
    or0[lane + 64 * j] = pack4((va[j][0] - mua) * rsa * wv.x + bv.x,
                               (va[j][1] - mua) * rsa * wv.y + bv.y,
                               (va[j][2] - mua) * rsa * wv.z + bv.z,
                               (va[j][3] - mua) * rsa * wv.w + bv.w);
    or1[lane + 64 * j] = pack4((vb[j][0] - mub) * rsb * wv.x + bv.x,
                               (vb[j][1] - mub) * rsb * wv.y + bv.y,
                               (vb[j][2] - mub) * rsb * wv.z + bv.z,
                               (vb[j][3] - mub) * rsb * wv.w + bv.w);
  }
}

// ---------------------------------------------------------------------------
// bf16 MFMA GEMM core: TM x 64 tile, BK=64 as two 32-col panels. LDS passed in.
// MODE 0: bf16 out
// MODE 1: f32 out
// MODE 2: bf16 out = f2bf(res_f32[o] + gamma[n]*(acc+bias))   (round-1 op)
// MODE 3: f32 out  = bf2f(res_bf16[o]) + gamma[n]*(acc+bias)  (round-2 op)
// ---------------------------------------------------------------------------
template <int TM, int MODE>
__device__ __forceinline__ void gemm_core(u16* __restrict__ As, u16* __restrict__ Bs,
                                          const u16* __restrict__ A, const u16* __restrict__ W,
                                          const float* __restrict__ bias, void* __restrict__ outv,
                                          const void* __restrict__ res, const float* __restrict__ gamma,
                                          int N, int K, int m0, int n0) {
  constexpr int FI = TM / 32;
  constexpr int NIA = TM / 32;
  const int tid = threadIdx.x;
  const int wv = tid >> 6, lane = tid & 63;
  const int quad = lane >> 4, l16 = lane & 15;
  const int wm = wv & 1, wn = wv >> 1;
  const int sr4 = lane >> 2;
  const int sc = (lane & 3) << 3;

  f32x4 acc[FI][2];
  #pragma unroll
  for (int i = 0; i < FI; ++i)
    #pragma unroll
    for (int j = 0; j < 2; ++j)
      acc[i][j] = (f32x4){0.f, 0.f, 0.f, 0.f};

  for (int k0 = 0; k0 < K; k0 += 64) {
    __syncthreads();
    #pragma unroll
    for (int j = 0; j < NIA; ++j) {
      const int g = wv * NIA + j;
      const int p = g & 1, rb = g >> 1;
      gl_lds16(A + (size_t)(m0 + rb * 16 + sr4) * K + (k0 + p * 32 + sc),
               (char*)As + p * (TM * 64) + rb * 1024 + lane * 16);
    }
    #pragma unroll
    for (int j = 0; j < 2; ++j) {
      const int g = wv * 2 + j;
      const int p = g & 1, rb = g >> 1;
      gl_lds16(W + (size_t)(n0 + rb * 16 + sr4) * K + (k0 + p * 32 + sc),
               (char*)Bs + p * 4096 + rb * 1024 + lane * 16);
    }
    __syncthreads();
    #pragma unroll
    for (int kk = 0; kk < 2; ++kk) {
      bf16x8 af[FI], bfr[2];
      #pragma unroll
      for (int i = 0; i < FI; ++i)
        af[i] = *(const bf16x8*)(As + kk * (TM * 32) + (wm * (TM / 2) + i * 16 + l16) * 32 + quad * 8);
      #pragma unroll
      for (int j = 0; j < 2; ++j)
        bfr[j] = *(const bf16x8*)(Bs + kk * 2048 + (wn * 32 + j * 16 + l16) * 32 + quad * 8);
      #pragma unroll
      for (int i = 0; i < FI; ++i)
        #pragma unroll
        for (int j = 0; j < 2; ++j)
          acc[i][j] = __builtin_amdgcn_mfma_f32_16x16x32_bf16(af[i], bfr[j], acc[i][j], 0, 0, 0);
    }
  }

  #pragma unroll
  for (int i = 0; i < FI; ++i) {
    #pragma unroll
    for (int j = 0; j < 2; ++j) {
      const int col = n0 + wn * 32 + j * 16 + l16;
      const float bs = bias[col];
      #pragma unroll
      for (int r = 0; r < 4; ++r) {
        const int row = m0 + wm * (TM / 2) + i * 16 + quad * 4 + r;
        const float v = acc[i][j][r] + bs;
        const size_t o = (size_t)row * N + col;
        if (MODE == 0) ((u16*)outv)[o] = f2bf(v);
        else if (MODE == 1) ((float*)outv)[o] = v;
        else if (MODE == 2) ((u16*)outv)[o] = f2bf(((const float*)res)[o] + gamma[col] * v);
        else ((float*)outv)[o] = bf2f(((const u16*)res)[o]) + gamma[col] * v;
      }
    }
  }
}

// Fused dispatch: both value-projection GEMMs (2x864 blocks, XCD-swizzled) +
// round-1 small offset/aw GEMM (288 blocks) in one 2016-block launch.
__global__ __launch_bounds__(256, 5)
void gemm_fused1(const u16* __restrict__ fn, const u16* __restrict__ wv1, const float* __restrict__ vb1, u16* __restrict__ val1,
                 const u16* __restrict__ fn2, const u16* __restrict__ wv2, const float* __restrict__ vb2, u16* __restrict__ val2,
                 const u16* __restrict__ qn, const u16* __restrict__ cat1, const float* __restrict__ b1, float* __restrict__ offaw) {
  __shared__ u16 As[128 * 64];
  __shared__ u16 Bs[64 * 64];
  const int id = blockIdx.x;
  if (id < 1728) {
    const int z = id / 864, rem = id - z * 864;
    int m0, n0;
    swz864(rem, m0, n0);
    gemm_core<128, 0>(As, Bs, z ? fn2 : fn, z ? wv2 : wv1, z ? vb2 : vb1,
                      (void*)(z ? val2 : val1), nullptr, nullptr, CC, CC, m0, n0);
  } else {
    const int sid = id - 1728;
    const int x = sid % 144, y = sid / 144;
    gemm_core<64, 1>(As, Bs, qn, cat1, b1, (void*)offaw, nullptr, nullptr, 128, CC, x * 64, y * 64);
  }
}

template <int MODE>
__global__ __launch_bounds__(256, 5)
void gemm_bt(const u16* __restrict__ A, const u16* __restrict__ W,
             const float* __restrict__ bias, void* __restrict__ outv,
             const void* __restrict__ res, const float* __restrict__ gamma,
             int N, int K) {
  __shared__ u16 As[128 * 64];
  __shared__ u16 Bs[64 * 64];
  int m0, n0;
  swz864(blockIdx.x, m0, n0);
  gemm_core<128, MODE>(As, Bs, A, W, bias, outv, res, gamma, N, K, m0, n0);
}

__global__ __launch_bounds__(256, 5)
void gemm_small(const u16* __restrict__ A, const u16* __restrict__ W,
                const float* __restrict__ bias, float* __restrict__ out,
                int N, int K) {
  __shared__ u16 As[64 * 64];
  __shared__ u16 Bs[64 * 64];
  gemm_core<64, 1>(As, Bs, A, W, bias, (void*)out, nullptr, nullptr, N, K, blockIdx.x * 64, blockIdx.y * 64);
}

// ---------------------------------------------------------------------------
// Deformable sampling: 16 lanes per (q,h), each lane 8 channels (dwordx4).
// All 16 corner loads batched (addresses+weights precomputed) for max MLP.
// ---------------------------------------------------------------------------
__global__ __launch_bounds__(256)
void msds_sample(const u16* __restrict__ value, const float* __restrict__ offaw,
                 const float* __restrict__ ref, u16* __restrict__ out) {
  const int t = blockIdx.x * 256 + threadIdx.x;
  const int pi = t >> 4;
  const int gl = t & 15;
  const int q = pi / NH;
  const int h = pi - q * NH;
  const float4* oaf = (const float4*)(offaw + (size_t)q * 128);
  const float4 of0 = oaf[h * 2];
  const float4 of1 = oaf[h * 2 + 1];
  const float4 lg = oaf[12 + h];
  const float2 rp = ((const float2*)ref)[q];
  const float rx = rp.x * (float)WW - 0.5f;
  const float ry = rp.y * (float)HH - 0.5f;

  const float mx = fmaxf(fmaxf(lg.x, lg.y), fmaxf(lg.z, lg.w));
  const float e0 = __expf(lg.x - mx), e1 = __expf(lg.y - mx);
  const float e2 = __expf(lg.z - mx), e3 = __expf(lg.w - mx);
  const float inv = 1.f / (e0 + e1 + e2 + e3);
  const float wp[4] = {e0 * inv, e1 * inv, e2 * inv, e3 * inv};
  const float ox[4] = {of0.x, of0.z, of1.x, of1.z};
  const float oy[4] = {of0.y, of0.w, of1.y, of1.w};

  const u16* vbase = value + h * DH + gl * 8;
  float w16[16];
  int  idx16[16];
  #pragma unroll
  for (int p = 0; p < 4; ++p) {
    const float px = rx + ox[p];
    const float py = ry + oy[p];
    const float fxf = floorf(px), fyf = floorf(py);
    const int x0 = (int)fxf, y0 = (int)fyf;
    const float fx = px - fxf, fy = py - fyf;
    const float cw[4] = {wp[p] * (1.f - fy) * (1.f - fx), wp[p] * (1.f - fy) * fx,
                         wp[p] * fy * (1.f - fx),         wp[p] * fy * fx};
    #pragma unroll
    for (int c = 0; c < 4; ++c) {
      const int yy = y0 + (c >> 1);
      const int xx = x0 + (c & 1);
      const bool valid = (yy >= 0) & (yy < HH) & (xx >= 0) & (xx < WW);
      const int yc = min(max(yy, 0), HH - 1);
      const int xc = min(max(xx, 0), WW - 1);
      w16[p * 4 + c] = valid ? cw[c] : 0.f;
      idx16[p * 4 + c] = yc * WW + xc;
    }
  }
  u32x4 d[16];
  #pragma unroll
  for (int tt = 0; tt < 16; ++tt)
    d[tt] = *(const u32x4*)(vbase + (size_t)idx16[tt] * CC);

  float acc[8];
  #pragma unroll
  for (int k = 0; k < 8; ++k) acc[k] = 0.f;
  #pragma unroll
  for (int tt = 0; tt < 16; ++tt) {
    const float w2 = w16[tt];
    #pragma unroll
    for (int k = 0; k < 4; ++k) {
      acc[2 * k]     += w2 * u2f(d[tt][k] << 16);
      acc[2 * k + 1] += w2 * u2f(d[tt][k] & 0xffff0000u);
    }
  }
  u32x4 o;
  #pragma unroll
  for (int k = 0; k < 4; ++k)
    o[k] = (u32)f2bf(acc[2 * k]) | ((u32)f2bf(acc[2 * k + 1]) << 16);
  *(u32x4*)(out + (size_t)q * CC + h * DH + gl * 8) = o;
}

// ---------------------------------------------------------------------------
extern "C" void kernel_launch(void* const* d_in, const int* in_sizes, int n_in,
                              void* d_out, int out_size, void* d_ws, size_t ws_size,
                              hipStream_t stream) {
  const float* query = (const float*)d_in[0];
  const float* refp  = (const float*)d_in[1];
  const float* feat  = (const float*)d_in[2];
  const float* feat2 = (const float*)d_in[3];
  const float* qn_w = (const float*)d_in[6];
  const float* qn_b = (const float*)d_in[7];
  const float* fn_w = (const float*)d_in[8];
  const float* fn_b = (const float*)d_in[9];
  const float* so_w = (const float*)d_in[10];
  const float* so_b = (const float*)d_in[11];
  const float* aw_w = (const float*)d_in[12];
  const float* aw_b = (const float*)d_in[13];
  const float* vp_w = (const float*)d_in[14];
  const float* vp_b = (const float*)d_in[15];
  const float* op_w = (const float*)d_in[16];
  const float* op_b = (const float*)d_in[17];
  const float* gamma = (const float*)d_in[18];
  const float* qn2_w = (const float*)d_in[19];
  const float* qn2_b = (const float*)d_in[20];
  const float* fn2_w = (const float*)d_in[21];
  const float* fn2_b = (const float*)d_in[22];
  const float* so2_w = (const float*)d_in[23];
  const float* so2_b = (const float*)d_in[24];
  const float* aw2_w = (const float*)d_in[25];
  const float* aw2_b = (const float*)d_in[26];
  const float* vp2_w = (const float*)d_in[27];
  const float* vp2_b = (const float*)d_in[28];
  const float* op2_w = (const float*)d_in[29];
  const float* op2_b = (const float*)d_in[30];
  const float* gamma2 = (const float*)d_in[31];

  char* ws = (char*)d_ws;
  size_t off = 0;
  auto alloc = [&](size_t bytes) -> void* {
    void* p = ws + off;
    off += (bytes + 255) & ~(size_t)255;
    return p;
  };
  u16* w4    = (u16*)alloc((size_t)4 * 589824 * 2);
  u16* cat1  = (u16*)alloc((size_t)98304 * 2);
  u16* cat2  = (u16*)alloc((size_t)98304 * 2);
  float* b1  = (float*)alloc(128 * 4);
  float* b2  = (float*)alloc(128 * 4);
  u16* qn    = (u16*)alloc((size_t)LQ * CC * 2);  // reused as qn2
  u16* fn    = (u16*)alloc((size_t)LQ * CC * 2);  // reused as a_pre
  u16* fn2   = (u16*)alloc((size_t)LQ * CC * 2);  // reused as a2_pre
  u16* val1  = (u16*)alloc((size_t)LQ * CC * 2);
  u16* val2  = (u16*)alloc((size_t)LQ * CC * 2);
  float* offaw = (float*)alloc((size_t)LQ * 128 * 4);  // both rounds
  u16* qbuf  = (u16*)alloc((size_t)LQ * CC * 2);       // bf16 residual q

  dim3 blk(256);
  dim3 gsm(LQ / 64, 2);

  prelude<<<PREP_BLKS + 3 * 1152, blk, 0, stream>>>(
      vp_w, op_w, vp2_w, op2_w, so_w, aw_w, so2_w, aw2_w,
      so_b, aw_b, so2_b, aw2_b, w4, cat1, cat2, b1, b2,
      query, qn_w, qn_b, qn,
      feat, fn_w, fn_b, fn,
      feat2, fn2_w, fn2_b, fn2);
  gemm_fused1<<<2016, blk, 0, stream>>>(fn, w4, vp_b, val1,
                                        fn2, w4 + 2 * 589824, vp2_b, val2,
                                        qn, cat1, b1, offaw);
  msds_sample<<<LQ * NH / 16, blk, 0, stream>>>(val1, offaw, refp, fn);  // a_pre -> fn
  gemm_bt<2><<<864, blk, 0, stream>>>(fn, w4 + 589824, op_b, (void*)qbuf, query, gamma, CC, CC);
  ln_bf16_to_bf16<<<LQ / 8, blk, 0, stream>>>(qbuf, qn2_w, qn2_b, qn);  // qn2 -> qn
  gemm_small<<<gsm, blk, 0, stream>>>(qn, cat2, b2, offaw, 128, CC);
  msds_sample<<<LQ * NH / 16, blk, 0, stream>>>(val2, offaw, refp, fn2);  // a2_pre -> fn2
  gemm_bt<3><<<864, blk, 0, stream>>>(fn2, w4 + 3 * 589824, op2_b, d_out, qbuf, gamma2, CC, CC);
}